// Round 5
// baseline (1752.070 us; speedup 1.0000x reference)
//
#include <hip/hip_runtime.h>
#include <hip/hip_fp16.h>

#define BLOCK 256
#define NB 1024        // target buckets (bucket span <= 65536 for tgt16 trick)
#define TILE 1024      // max atoms per bucket (N <= NB*TILE for fast path)
#define GP 512         // grid for hist/place (keeps L2 open-line budget)
#define KSLICE 4       // accum slices per bucket (partial acc arrays)
#define KS_TOT (KSLICE + 1)   // + overflow partial

// no-return LDS atomic add (forces ds_add_f32, no lgkmcnt chain)
__device__ __forceinline__ void lds_fadd(float* p, float v) {
    (void)__hip_atomic_fetch_add(p, v, __ATOMIC_RELAXED, __HIP_MEMORY_SCOPE_WORKGROUP);
}

// ---------------- offsets scan (tiny) ----------------
__global__ void scan_offsets_kernel(const int* __restrict__ num_atoms, int B,
                                    int* __restrict__ offsets) {
    __shared__ long long partial[1024];
    int t = threadIdx.x;
    int per = (B + 1023) / 1024;
    int base_idx = t * per;
    long long local = 0;
    for (int i = 0; i < per; ++i) {
        int idx = base_idx + i;
        if (idx < B) local += num_atoms[idx];
    }
    partial[t] = local;
    __syncthreads();
    for (int d = 1; d < 1024; d <<= 1) {
        long long v = (t >= d) ? partial[t - d] : 0;
        __syncthreads();
        partial[t] += v;
        __syncthreads();
    }
    long long run = (t == 0) ? 0 : partial[t - 1];
    for (int i = 0; i < per; ++i) {
        int idx = base_idx + i;
        if (idx < B) {
            offsets[idx] = (int)run;
            run += num_atoms[idx];
        }
    }
    if (t == 1023) offsets[B] = (int)partial[1023];
}

__device__ __forceinline__ int find_batch(const int* __restrict__ offsets, int B, int n) {
    int lo = 0, hi = B;
    while (hi - lo > 1) {
        int mid = (lo + hi) >> 1;
        if (offsets[mid] <= n) lo = mid; else hi = mid;
    }
    return lo;
}

// ---------------- scaled = inv_lat^T f ; zero partial slices [zf,zt) ----------------
__global__ void scale_kernel(const float* __restrict__ inv_lat,
                             const float* __restrict__ forces,
                             const int* __restrict__ offsets, int B, int N,
                             float* __restrict__ scaled, float* __restrict__ partials,
                             int zf, int zt) {
    int n = blockIdx.x * blockDim.x + threadIdx.x;
    if (n >= N) return;
    int b = find_batch(offsets, B, n);
    const float* M = inv_lat + (size_t)b * 9;
    float f0 = forces[n * 3 + 0], f1 = forces[n * 3 + 1], f2 = forces[n * 3 + 2];
    float s0 = M[0] * f0 + M[3] * f1 + M[6] * f2;
    float s1 = M[1] * f0 + M[4] * f1 + M[7] * f2;
    float s2 = M[2] * f0 + M[5] * f1 + M[8] * f2;
    scaled[n * 3 + 0] = s0; scaled[n * 3 + 1] = s1; scaled[n * 3 + 2] = s2;
    for (int k = zf; k < zt; ++k) {
        float* a = partials + (size_t)k * N * 3;
        a[n * 3 + 0] = 0.f; a[n * 3 + 1] = 0.f; a[n * 3 + 2] = 0.f;
    }
}

__device__ __forceinline__ int bucket_of(int tgt, int N) {
    return (int)(((unsigned long long)(unsigned)tgt * (unsigned)NB) / (unsigned)N);
}

// ---------------- pass 1: per-block bucket histogram (2x int4 unroll) ----------------
__global__ __launch_bounds__(BLOCK) void hist_kernel(const int* __restrict__ symm_map,
                            long long chunk_base, int chunk_pairs, int N,
                            int* __restrict__ hist) {
    __shared__ int h[NB];
    int tid = threadIdx.x;
    for (int i = tid; i < NB; i += BLOCK) h[i] = 0;
    __syncthreads();
    int nblk = gridDim.x;
    const int quantum = 4 * BLOCK;
    int span = (int)(((long long)chunk_pairs + (long long)nblk * quantum - 1) / ((long long)nblk * quantum)) * quantum;
    long long bs = (long long)blockIdx.x * span;
    int cnt = (int)((chunk_pairs - bs) < (long long)span ? (chunk_pairs - bs) : (long long)span);
    if (cnt > 0) {
        const int* p = symm_map + chunk_base + bs;
        int i0 = tid * 4;
        for (; i0 + 4 + quantum <= cnt; i0 += 2 * quantum) {
            int4 va = *(const int4*)(p + i0);
            int4 vb = *(const int4*)(p + i0 + quantum);
            atomicAdd(&h[bucket_of(va.x, N)], 1);
            atomicAdd(&h[bucket_of(va.y, N)], 1);
            atomicAdd(&h[bucket_of(va.z, N)], 1);
            atomicAdd(&h[bucket_of(va.w, N)], 1);
            atomicAdd(&h[bucket_of(vb.x, N)], 1);
            atomicAdd(&h[bucket_of(vb.y, N)], 1);
            atomicAdd(&h[bucket_of(vb.z, N)], 1);
            atomicAdd(&h[bucket_of(vb.w, N)], 1);
        }
        for (; i0 + 4 <= cnt; i0 += quantum) {
            int4 v = *(const int4*)(p + i0);
            atomicAdd(&h[bucket_of(v.x, N)], 1);
            atomicAdd(&h[bucket_of(v.y, N)], 1);
            atomicAdd(&h[bucket_of(v.z, N)], 1);
            atomicAdd(&h[bucket_of(v.w, N)], 1);
        }
        if (i0 < cnt) {
            for (int j = i0; j < cnt; ++j)
                atomicAdd(&h[bucket_of(p[j], N)], 1);
        }
    }
    __syncthreads();
    for (int i = tid; i < NB; i += BLOCK) hist[(size_t)blockIdx.x * NB + i] = h[i];
}

// ---------------- pass 2: per-bucket exclusive scan over GP blocks ----------------
__global__ __launch_bounds__(BLOCK) void scan_cols_kernel(const int* __restrict__ hist, int cap,
                                 int* __restrict__ offs, int* __restrict__ cnt) {
    const int K = GP / BLOCK;
    int b = blockIdx.x, tid = threadIdx.x;
    int v[K];
    int sum = 0;
    for (int k = 0; k < K; ++k) {
        v[k] = hist[(size_t)(tid * K + k) * NB + b];
        sum += v[k];
    }
    __shared__ int s[BLOCK];
    s[tid] = sum;
    __syncthreads();
    for (int d = 1; d < BLOCK; d <<= 1) {
        int x = (tid >= d) ? s[tid - d] : 0;
        __syncthreads();
        s[tid] += x;
        __syncthreads();
    }
    int run = b * cap + ((tid == 0) ? 0 : s[tid - 1]);
    for (int k = 0; k < K; ++k) {
        offs[(size_t)(tid * K + k) * NB + b] = run;
        run += v[k];
    }
    if (tid == BLOCK - 1) cnt[b] = (s[BLOCK - 1] < cap) ? s[BLOCK - 1] : cap;
}

// ---------------- pass 3: place 8B records grouped by bucket ----------------
// record = uint2 { h(v0) | h(v1)<<16 , h(v2) | (tgt&0xFFFF)<<16 }
__global__ __launch_bounds__(BLOCK) void place_kernel(const int* __restrict__ symm_map,
                             const float* __restrict__ scaled,
                             const float* __restrict__ general_ops,
                             const int* __restrict__ offs,
                             long long chunk_base, int chunk_pairs, int N, int O, int cap,
                             uint2* __restrict__ records, float* __restrict__ ovf) {
    __shared__ int cur[NB];
    __shared__ float R[64 * 9];
    int tid = threadIdx.x;
    for (int i = tid; i < O * 9; i += BLOCK) {
        int o = i / 9, r = i - o * 9;
        R[i] = general_ops[o * 16 + (r / 3) * 4 + (r % 3)];
    }
    for (int i = tid; i < NB; i += BLOCK) cur[i] = offs[(size_t)blockIdx.x * NB + i];
    __syncthreads();
    int nblk = gridDim.x;
    const int quantum = 4 * BLOCK;
    int span = (int)(((long long)chunk_pairs + (long long)nblk * quantum - 1) / ((long long)nblk * quantum)) * quantum;
    long long bs = (long long)blockIdx.x * span;
    int cnt = (int)((chunk_pairs - bs) < (long long)span ? (chunk_pairs - bs) : (long long)span);
    if (cnt <= 0) return;
    const int* p = symm_map + chunk_base + bs;
    unsigned tbase = (unsigned)(chunk_base + bs);
    unsigned uO = (unsigned)O;
    int i0 = tid * 4;
    unsigned t0 = tbase + (unsigned)i0;
    unsigned n = t0 / uO;
    unsigned o = t0 - n * uO;
    unsigned dq = (unsigned)quantum / uO;
    unsigned rq = (unsigned)quantum - dq * uO;
    for (; i0 + 4 <= cnt; i0 += quantum) {
        int4 tg = *(const int4*)(p + i0);
        unsigned nn = n, oo = o;
        #pragma unroll
        for (int j = 0; j < 4; ++j) {
            int tgt = (j == 0) ? tg.x : (j == 1) ? tg.y : (j == 2) ? tg.z : tg.w;
            const float* Ro = R + oo * 9;
            float s0 = scaled[nn * 3 + 0], s1 = scaled[nn * 3 + 1], s2 = scaled[nn * 3 + 2];
            float v0 = Ro[0] * s0 + Ro[1] * s1 + Ro[2] * s2;
            float v1 = Ro[3] * s0 + Ro[4] * s1 + Ro[5] * s2;
            float v2 = Ro[6] * s0 + Ro[7] * s1 + Ro[8] * s2;
            int bb = bucket_of(tgt, N);
            int pos = atomicAdd(&cur[bb], 1);
            if (pos - bb * cap < cap) {
                unsigned x = (unsigned)__half_as_ushort(__float2half_rn(v0)) |
                             ((unsigned)__half_as_ushort(__float2half_rn(v1)) << 16);
                unsigned y = (unsigned)__half_as_ushort(__float2half_rn(v2)) |
                             (((unsigned)tgt & 0xFFFFu) << 16);
                records[pos] = make_uint2(x, y);
            } else {
                atomicAdd(&ovf[(size_t)tgt * 3 + 0], v0);
                atomicAdd(&ovf[(size_t)tgt * 3 + 1], v1);
                atomicAdd(&ovf[(size_t)tgt * 3 + 2], v2);
            }
            if (++oo == uO) { oo = 0; ++nn; }
        }
        o += rq;
        if (o >= uO) { o -= uO; n += dq + 1; } else n += dq;
    }
    if (i0 < cnt) {
        unsigned nn = n, oo = o;
        for (int j = i0; j < cnt; ++j) {
            int tgt = p[j];
            const float* Ro = R + oo * 9;
            float s0 = scaled[nn * 3 + 0], s1 = scaled[nn * 3 + 1], s2 = scaled[nn * 3 + 2];
            float v0 = Ro[0] * s0 + Ro[1] * s1 + Ro[2] * s2;
            float v1 = Ro[3] * s0 + Ro[4] * s1 + Ro[5] * s2;
            float v2 = Ro[6] * s0 + Ro[7] * s1 + Ro[8] * s2;
            int bb = bucket_of(tgt, N);
            int pos = atomicAdd(&cur[bb], 1);
            if (pos - bb * cap < cap) {
                unsigned x = (unsigned)__half_as_ushort(__float2half_rn(v0)) |
                             ((unsigned)__half_as_ushort(__float2half_rn(v1)) << 16);
                unsigned y = (unsigned)__half_as_ushort(__float2half_rn(v2)) |
                             (((unsigned)tgt & 0xFFFFu) << 16);
                records[pos] = make_uint2(x, y);
            } else {
                atomicAdd(&ovf[(size_t)tgt * 3 + 0], v0);
                atomicAdd(&ovf[(size_t)tgt * 3 + 1], v1);
                atomicAdd(&ovf[(size_t)tgt * 3 + 2], v2);
            }
            if (++oo == uO) { oo = 0; ++nn; }
        }
    }
}

// ---------------- pass 4: per-(bucket,slice) LDS accumulation into partials ----------------
__device__ __forceinline__ void accum_rec2(float* accL, unsigned x, unsigned y, int lo16) {
    float v0 = __half2float(__ushort_as_half((unsigned short)(x & 0xFFFF)));
    float v1 = __half2float(__ushort_as_half((unsigned short)(x >> 16)));
    float v2 = __half2float(__ushort_as_half((unsigned short)(y & 0xFFFF)));
    int local = ((int)(y >> 16) - lo16) & 0xFFFF;
    lds_fadd(&accL[local * 3 + 0], v0);
    lds_fadd(&accL[local * 3 + 1], v1);
    lds_fadd(&accL[local * 3 + 2], v2);
}

__global__ __launch_bounds__(BLOCK) void accum_kernel(const uint2* __restrict__ records,
                             const int* __restrict__ cnt, int N, int cap,
                             float* __restrict__ partials, int store_mode) {
    __shared__ float accL[TILE * 3];
    int b = blockIdx.x >> 2;          // KSLICE == 4
    int k = blockIdx.x & 3;
    int tid = threadIdx.x;
    int lo = (int)(((long long)b * N + NB - 1) / NB);
    int hi = (int)(((long long)(b + 1) * N + NB - 1) / NB);
    if (hi > N) hi = N;
    int span3 = (hi - lo) * 3;
    for (int i = tid; i < span3; i += BLOCK) accL[i] = 0.f;
    __syncthreads();
    int c = cnt[b];
    int per = (((c + KSLICE - 1) / KSLICE) + 1) & ~1;  // even -> slice start 16B-aligned
    int s0i = k * per; if (s0i > c) s0i = c;
    int s1i = s0i + per; if (s1i > c) s1i = c;
    int myc = s1i - s0i;
    const uint2* r = records + (size_t)b * cap + s0i;
    int lo16 = lo & 0xFFFF;
    const uint4* r4 = (const uint4*)r;
    int pairs = myc >> 1;
    int i = tid;
    for (; i + 3 * BLOCK < pairs; i += 4 * BLOCK) {
        uint4 f0 = r4[i];
        uint4 f1 = r4[i + BLOCK];
        uint4 f2 = r4[i + 2 * BLOCK];
        uint4 f3 = r4[i + 3 * BLOCK];
        accum_rec2(accL, f0.x, f0.y, lo16); accum_rec2(accL, f0.z, f0.w, lo16);
        accum_rec2(accL, f1.x, f1.y, lo16); accum_rec2(accL, f1.z, f1.w, lo16);
        accum_rec2(accL, f2.x, f2.y, lo16); accum_rec2(accL, f2.z, f2.w, lo16);
        accum_rec2(accL, f3.x, f3.y, lo16); accum_rec2(accL, f3.z, f3.w, lo16);
    }
    for (; i < pairs; i += BLOCK) {
        uint4 f = r4[i];
        accum_rec2(accL, f.x, f.y, lo16); accum_rec2(accL, f.z, f.w, lo16);
    }
    if (tid == 0 && (myc & 1)) {
        uint2 f = r[myc - 1];
        accum_rec2(accL, f.x, f.y, lo16);
    }
    __syncthreads();
    float* g = partials + (size_t)k * N * 3 + (size_t)lo * 3;
    if (store_mode) {
        for (int q = tid; q < span3; q += BLOCK) g[q] = accL[q];
    } else {
        for (int q = tid; q < span3; q += BLOCK) g[q] += accL[q];
    }
}

// ---------------- fallback scatter (device atomics) ----------------
__global__ void scatter_kernel(const float* __restrict__ scaled,
                               const float* __restrict__ general_ops,
                               const int* __restrict__ symm_map,
                               float* __restrict__ acc,
                               long long total, int O) {
    __shared__ float rot_s[64 * 9];
    for (int i = threadIdx.x; i < O * 9; i += blockDim.x) {
        int o = i / 9, r = i - o * 9;
        rot_s[i] = general_ops[o * 16 + (r / 3) * 4 + (r % 3)];
    }
    __syncthreads();
    long long t = (long long)blockIdx.x * blockDim.x + threadIdx.x;
    if (t >= total) return;
    long long n = t / O;
    int o = (int)(t - n * O);
    float s0 = scaled[n * 3 + 0], s1 = scaled[n * 3 + 1], s2 = scaled[n * 3 + 2];
    const float* R = rot_s + o * 9;
    float v0 = R[0] * s0 + R[1] * s1 + R[2] * s2;
    float v1 = R[3] * s0 + R[4] * s1 + R[5] * s2;
    float v2 = R[6] * s0 + R[7] * s1 + R[8] * s2;
    int tgt = symm_map[t];
    atomicAdd(&acc[(size_t)tgt * 3 + 0], v0);
    atomicAdd(&acc[(size_t)tgt * 3 + 1], v1);
    atomicAdd(&acc[(size_t)tgt * 3 + 2], v2);
}

// ---------------- out = lat^T (sum_k partial_k / count) ----------------
__global__ void output_kernel(const float* __restrict__ lat,
                              const int* __restrict__ num_general_ops,
                              const int* __restrict__ offsets, int B, int N,
                              const float* __restrict__ partials, int K,
                              float* __restrict__ out) {
    int n = blockIdx.x * blockDim.x + threadIdx.x;
    if (n >= N) return;
    int b = find_batch(offsets, B, n);
    float inv_cnt = 1.0f / (float)num_general_ops[b];
    float a0 = 0.f, a1 = 0.f, a2 = 0.f;
    for (int k = 0; k < K; ++k) {
        const float* a = partials + (size_t)k * N * 3;
        a0 += a[n * 3 + 0]; a1 += a[n * 3 + 1]; a2 += a[n * 3 + 2];
    }
    a0 *= inv_cnt; a1 *= inv_cnt; a2 *= inv_cnt;
    const float* M = lat + (size_t)b * 9;
    out[n * 3 + 0] = M[0] * a0 + M[3] * a1 + M[6] * a2;
    out[n * 3 + 1] = M[1] * a0 + M[4] * a1 + M[7] * a2;
    out[n * 3 + 2] = M[2] * a0 + M[5] * a1 + M[8] * a2;
}

static inline size_t align16(size_t x) { return (x + 15) & ~(size_t)15; }

extern "C" void kernel_launch(void* const* d_in, const int* in_sizes, int n_in,
                              void* d_out, int out_size, void* d_ws, size_t ws_size,
                              hipStream_t stream) {
    const float* lattices        = (const float*)d_in[0];
    const float* inv_lattices    = (const float*)d_in[1];
    const float* forces          = (const float*)d_in[2];
    const int*   num_atoms       = (const int*)d_in[3];
    const float* general_ops     = (const float*)d_in[4];
    const int*   symm_map        = (const int*)d_in[5];
    const int*   num_general_ops = (const int*)d_in[6];

    int B = in_sizes[0] / 9;
    int N = in_sizes[2] / 3;
    int O = in_sizes[4] / 16;
    long long total = (long long)N * O;

    // ---- workspace layout ----
    char* p = (char*)d_ws;
    size_t used = 0;
    float* scaled   = (float*)(p + used); used = align16(used + (size_t)N * 3 * sizeof(float));
    float* partials = (float*)(p + used); used = align16(used + (size_t)KS_TOT * N * 3 * sizeof(float));
    int* offsets    = (int*)(p + used);   used = align16(used + (size_t)(B + 1) * sizeof(int));
    int* hist       = (int*)(p + used);   used = align16(used + (size_t)GP * NB * sizeof(int));
    int* offs       = (int*)(p + used);   used = align16(used + (size_t)GP * NB * sizeof(int));
    int* cnt        = (int*)(p + used);   used = align16(used + (size_t)NB * sizeof(int));
    size_t remaining = (ws_size > used) ? ws_size - used : 0;

    // choose chunk count C so 8B records fit; cap = mean + 25% + 512 slack, even
    const long long quantum = 4 * BLOCK;
    int C = -1, cap = 0;
    long long chunk_nom = 0;
    for (int c = 1; c <= 64; ++c) {
        long long cp = (total + c - 1) / c;
        cp = (cp + quantum - 1) / quantum * quantum;
        long long mean = (cp + NB - 1) / NB;
        long long capc = mean + mean / 4 + 512;
        capc = (capc + 1) & ~1LL;  // even, for uint4 alignment
        if ((size_t)NB * capc * sizeof(uint2) <= remaining) { C = c; cap = (int)capc; chunk_nom = cp; break; }
    }
    bool fast = (C > 0) && ((long long)N <= (long long)NB * TILE) && (O <= 64) && (total < (1LL << 31));

    int gridN = (N + BLOCK - 1) / BLOCK;
    scan_offsets_kernel<<<1, 1024, 0, stream>>>(num_atoms, B, offsets);

    if (fast) {
        uint2* records = (uint2*)(p + used);
        float* ovf = partials + (size_t)KSLICE * N * 3;
        int store_mode = (C == 1) ? 1 : 0;
        int zf = store_mode ? KSLICE : 0;    // store-mode: only zero overflow slice
        scale_kernel<<<gridN, BLOCK, 0, stream>>>(inv_lattices, forces, offsets, B, N,
                                                  scaled, partials, zf, KS_TOT);
        for (int c = 0; c < C; ++c) {
            long long base = (long long)c * chunk_nom;
            if (base >= total) break;
            long long rem = total - base;
            int cp = (int)((rem < chunk_nom) ? rem : chunk_nom);
            hist_kernel<<<GP, BLOCK, 0, stream>>>(symm_map, base, cp, N, hist);
            scan_cols_kernel<<<NB, BLOCK, 0, stream>>>(hist, cap, offs, cnt);
            place_kernel<<<GP, BLOCK, 0, stream>>>(symm_map, scaled, general_ops, offs,
                                                   base, cp, N, O, cap, records, ovf);
            accum_kernel<<<NB * KSLICE, BLOCK, 0, stream>>>(records, cnt, N, cap, partials, store_mode);
        }
        output_kernel<<<gridN, BLOCK, 0, stream>>>(lattices, num_general_ops, offsets, B, N,
                                                   partials, KS_TOT, (float*)d_out);
    } else {
        // fallback: device-atomic scatter into partials[0]
        scale_kernel<<<gridN, BLOCK, 0, stream>>>(inv_lattices, forces, offsets, B, N,
                                                  scaled, partials, 0, 1);
        long long gridS = (total + BLOCK - 1) / BLOCK;
        scatter_kernel<<<(int)gridS, BLOCK, 0, stream>>>(scaled, general_ops, symm_map, partials, total, O);
        output_kernel<<<gridN, BLOCK, 0, stream>>>(lattices, num_general_ops, offsets, B, N,
                                                   partials, 1, (float*)d_out);
    }
}

// Round 6
// 1225.883 us; speedup vs baseline: 1.4292x; 1.4292x over previous
//
#include <hip/hip_runtime.h>
#include <hip/hip_fp16.h>

#define BLOCK 256
#define NB 1024        // target buckets (bucket span <= 65536 for tgt16 trick)
#define TILE 1024      // max atoms per bucket (N <= NB*TILE for fast path)
#define GP 512         // grid for hist/place (keeps L2 open-line budget)
#define KSLICE 4       // accum slices per bucket (partial acc arrays)
#define KS_TOT (KSLICE + 1)   // + overflow partial

// ---------------- offsets scan (tiny) ----------------
__global__ void scan_offsets_kernel(const int* __restrict__ num_atoms, int B,
                                    int* __restrict__ offsets) {
    __shared__ long long partial[1024];
    int t = threadIdx.x;
    int per = (B + 1023) / 1024;
    int base_idx = t * per;
    long long local = 0;
    for (int i = 0; i < per; ++i) {
        int idx = base_idx + i;
        if (idx < B) local += num_atoms[idx];
    }
    partial[t] = local;
    __syncthreads();
    for (int d = 1; d < 1024; d <<= 1) {
        long long v = (t >= d) ? partial[t - d] : 0;
        __syncthreads();
        partial[t] += v;
        __syncthreads();
    }
    long long run = (t == 0) ? 0 : partial[t - 1];
    for (int i = 0; i < per; ++i) {
        int idx = base_idx + i;
        if (idx < B) {
            offsets[idx] = (int)run;
            run += num_atoms[idx];
        }
    }
    if (t == 1023) offsets[B] = (int)partial[1023];
}

__device__ __forceinline__ int find_batch(const int* __restrict__ offsets, int B, int n) {
    int lo = 0, hi = B;
    while (hi - lo > 1) {
        int mid = (lo + hi) >> 1;
        if (offsets[mid] <= n) lo = mid; else hi = mid;
    }
    return lo;
}

// ---------------- scaled = inv_lat^T f ; zero partial slices [zf,zt) ----------------
__global__ void scale_kernel(const float* __restrict__ inv_lat,
                             const float* __restrict__ forces,
                             const int* __restrict__ offsets, int B, int N,
                             float* __restrict__ scaled, float* __restrict__ partials,
                             int zf, int zt) {
    int n = blockIdx.x * blockDim.x + threadIdx.x;
    if (n >= N) return;
    int b = find_batch(offsets, B, n);
    const float* M = inv_lat + (size_t)b * 9;
    float f0 = forces[n * 3 + 0], f1 = forces[n * 3 + 1], f2 = forces[n * 3 + 2];
    float s0 = M[0] * f0 + M[3] * f1 + M[6] * f2;
    float s1 = M[1] * f0 + M[4] * f1 + M[7] * f2;
    float s2 = M[2] * f0 + M[5] * f1 + M[8] * f2;
    scaled[n * 3 + 0] = s0; scaled[n * 3 + 1] = s1; scaled[n * 3 + 2] = s2;
    for (int k = zf; k < zt; ++k) {
        float* a = partials + (size_t)k * N * 3;
        a[n * 3 + 0] = 0.f; a[n * 3 + 1] = 0.f; a[n * 3 + 2] = 0.f;
    }
}

__device__ __forceinline__ int bucket_of(int tgt, int N) {
    return (int)(((unsigned long long)(unsigned)tgt * (unsigned)NB) / (unsigned)N);
}

// ---------------- pass 1: per-block bucket histogram (2x int4 unroll) ----------------
__global__ __launch_bounds__(BLOCK) void hist_kernel(const int* __restrict__ symm_map,
                            long long chunk_base, int chunk_pairs, int N,
                            int* __restrict__ hist) {
    __shared__ int h[NB];
    int tid = threadIdx.x;
    for (int i = tid; i < NB; i += BLOCK) h[i] = 0;
    __syncthreads();
    int nblk = gridDim.x;
    const int quantum = 4 * BLOCK;
    int span = (int)(((long long)chunk_pairs + (long long)nblk * quantum - 1) / ((long long)nblk * quantum)) * quantum;
    long long bs = (long long)blockIdx.x * span;
    int cnt = (int)((chunk_pairs - bs) < (long long)span ? (chunk_pairs - bs) : (long long)span);
    if (cnt > 0) {
        const int* p = symm_map + chunk_base + bs;
        int i0 = tid * 4;
        for (; i0 + 4 + quantum <= cnt; i0 += 2 * quantum) {
            int4 va = *(const int4*)(p + i0);
            int4 vb = *(const int4*)(p + i0 + quantum);
            atomicAdd(&h[bucket_of(va.x, N)], 1);
            atomicAdd(&h[bucket_of(va.y, N)], 1);
            atomicAdd(&h[bucket_of(va.z, N)], 1);
            atomicAdd(&h[bucket_of(va.w, N)], 1);
            atomicAdd(&h[bucket_of(vb.x, N)], 1);
            atomicAdd(&h[bucket_of(vb.y, N)], 1);
            atomicAdd(&h[bucket_of(vb.z, N)], 1);
            atomicAdd(&h[bucket_of(vb.w, N)], 1);
        }
        for (; i0 + 4 <= cnt; i0 += quantum) {
            int4 v = *(const int4*)(p + i0);
            atomicAdd(&h[bucket_of(v.x, N)], 1);
            atomicAdd(&h[bucket_of(v.y, N)], 1);
            atomicAdd(&h[bucket_of(v.z, N)], 1);
            atomicAdd(&h[bucket_of(v.w, N)], 1);
        }
        if (i0 < cnt) {
            for (int j = i0; j < cnt; ++j)
                atomicAdd(&h[bucket_of(p[j], N)], 1);
        }
    }
    __syncthreads();
    for (int i = tid; i < NB; i += BLOCK) hist[(size_t)blockIdx.x * NB + i] = h[i];
}

// ---------------- pass 2: per-bucket exclusive scan over GP blocks ----------------
__global__ __launch_bounds__(BLOCK) void scan_cols_kernel(const int* __restrict__ hist, int cap,
                                 int* __restrict__ offs, int* __restrict__ cnt) {
    const int K = GP / BLOCK;
    int b = blockIdx.x, tid = threadIdx.x;
    int v[K];
    int sum = 0;
    for (int k = 0; k < K; ++k) {
        v[k] = hist[(size_t)(tid * K + k) * NB + b];
        sum += v[k];
    }
    __shared__ int s[BLOCK];
    s[tid] = sum;
    __syncthreads();
    for (int d = 1; d < BLOCK; d <<= 1) {
        int x = (tid >= d) ? s[tid - d] : 0;
        __syncthreads();
        s[tid] += x;
        __syncthreads();
    }
    int run = b * cap + ((tid == 0) ? 0 : s[tid - 1]);
    for (int k = 0; k < K; ++k) {
        offs[(size_t)(tid * K + k) * NB + b] = run;
        run += v[k];
    }
    if (tid == BLOCK - 1) cnt[b] = (s[BLOCK - 1] < cap) ? s[BLOCK - 1] : cap;
}

// ---------------- record emit helper (place) ----------------
// |v| < 15 guaranteed for packed path; else neutral zero-record + ovf atomics.
__device__ __forceinline__ void emit_record(uint2* __restrict__ records,
                                            float* __restrict__ ovf,
                                            int* cur, int cap,
                                            int tgt, int bb,
                                            float v0, float v1, float v2) {
    int pos = atomicAdd(&cur[bb], 1);
    bool have_slot = (pos - bb * cap) < cap;
    float m = fmaxf(fmaxf(fabsf(v0), fabsf(v1)), fabsf(v2));
    if (have_slot && m < 15.0f) {
        unsigned x = (unsigned)__half_as_ushort(__float2half_rn(v0)) |
                     ((unsigned)__half_as_ushort(__float2half_rn(v1)) << 16);
        unsigned y = (unsigned)__half_as_ushort(__float2half_rn(v2)) |
                     (((unsigned)tgt & 0xFFFFu) << 16);
        records[pos] = make_uint2(x, y);
    } else {
        if (have_slot) {
            // keep slot dense: neutral zero-value record (bias math cancels it)
            records[pos] = make_uint2(0u, ((unsigned)tgt & 0xFFFFu) << 16);
        }
        atomicAdd(&ovf[(size_t)tgt * 3 + 0], v0);
        atomicAdd(&ovf[(size_t)tgt * 3 + 1], v1);
        atomicAdd(&ovf[(size_t)tgt * 3 + 2], v2);
    }
}

// ---------------- pass 3: place 8B records grouped by bucket ----------------
__global__ __launch_bounds__(BLOCK) void place_kernel(const int* __restrict__ symm_map,
                             const float* __restrict__ scaled,
                             const float* __restrict__ general_ops,
                             const int* __restrict__ offs,
                             long long chunk_base, int chunk_pairs, int N, int O, int cap,
                             uint2* __restrict__ records, float* __restrict__ ovf) {
    __shared__ int cur[NB];
    __shared__ float R[64 * 9];
    int tid = threadIdx.x;
    for (int i = tid; i < O * 9; i += BLOCK) {
        int o = i / 9, r = i - o * 9;
        R[i] = general_ops[o * 16 + (r / 3) * 4 + (r % 3)];
    }
    for (int i = tid; i < NB; i += BLOCK) cur[i] = offs[(size_t)blockIdx.x * NB + i];
    __syncthreads();
    int nblk = gridDim.x;
    const int quantum = 4 * BLOCK;
    int span = (int)(((long long)chunk_pairs + (long long)nblk * quantum - 1) / ((long long)nblk * quantum)) * quantum;
    long long bs = (long long)blockIdx.x * span;
    int cnt = (int)((chunk_pairs - bs) < (long long)span ? (chunk_pairs - bs) : (long long)span);
    if (cnt <= 0) return;
    const int* p = symm_map + chunk_base + bs;
    unsigned tbase = (unsigned)(chunk_base + bs);
    unsigned uO = (unsigned)O;
    int i0 = tid * 4;
    unsigned t0 = tbase + (unsigned)i0;
    unsigned n = t0 / uO;
    unsigned o = t0 - n * uO;
    unsigned dq = (unsigned)quantum / uO;
    unsigned rq = (unsigned)quantum - dq * uO;
    for (; i0 + 4 <= cnt; i0 += quantum) {
        int4 tg = *(const int4*)(p + i0);
        unsigned nn = n, oo = o;
        #pragma unroll
        for (int j = 0; j < 4; ++j) {
            int tgt = (j == 0) ? tg.x : (j == 1) ? tg.y : (j == 2) ? tg.z : tg.w;
            const float* Ro = R + oo * 9;
            float s0 = scaled[nn * 3 + 0], s1 = scaled[nn * 3 + 1], s2 = scaled[nn * 3 + 2];
            float v0 = Ro[0] * s0 + Ro[1] * s1 + Ro[2] * s2;
            float v1 = Ro[3] * s0 + Ro[4] * s1 + Ro[5] * s2;
            float v2 = Ro[6] * s0 + Ro[7] * s1 + Ro[8] * s2;
            emit_record(records, ovf, cur, cap, tgt, bucket_of(tgt, N), v0, v1, v2);
            if (++oo == uO) { oo = 0; ++nn; }
        }
        o += rq;
        if (o >= uO) { o -= uO; n += dq + 1; } else n += dq;
    }
    if (i0 < cnt) {
        unsigned nn = n, oo = o;
        for (int j = i0; j < cnt; ++j) {
            int tgt = p[j];
            const float* Ro = R + oo * 9;
            float s0 = scaled[nn * 3 + 0], s1 = scaled[nn * 3 + 1], s2 = scaled[nn * 3 + 2];
            float v0 = Ro[0] * s0 + Ro[1] * s1 + Ro[2] * s2;
            float v1 = Ro[3] * s0 + Ro[4] * s1 + Ro[5] * s2;
            float v2 = Ro[6] * s0 + Ro[7] * s1 + Ro[8] * s2;
            emit_record(records, ovf, cur, cap, tgt, bucket_of(tgt, N), v0, v1, v2);
            if (++oo == uO) { oo = 0; ++nn; }
        }
    }
}

// ---------------- pass 4: per-(bucket,slice) packed-u64 LDS accumulation ----------------
// accL word: [count:10 | q0:18 | q1:18 | q2:18], q = round((v+16)*32) in [0,1024)
__device__ __forceinline__ void accum_rec(unsigned long long* accL,
                                          unsigned x, unsigned y, int lo16) {
    float v0 = __half2float(__ushort_as_half((unsigned short)(x & 0xFFFF)));
    float v1 = __half2float(__ushort_as_half((unsigned short)(x >> 16)));
    float v2 = __half2float(__ushort_as_half((unsigned short)(y & 0xFFFF)));
    int local = ((int)(y >> 16) - lo16) & 0xFFFF;
    unsigned q0 = (unsigned)(int)rintf(fminf(fmaxf(v0, -15.97f), 15.96f) * 32.f + 512.f);
    unsigned q1 = (unsigned)(int)rintf(fminf(fmaxf(v1, -15.97f), 15.96f) * 32.f + 512.f);
    unsigned q2 = (unsigned)(int)rintf(fminf(fmaxf(v2, -15.97f), 15.96f) * 32.f + 512.f);
    unsigned long long u = (1ULL << 54) | ((unsigned long long)q0 << 36)
                         | ((unsigned long long)q1 << 18) | (unsigned long long)q2;
    (void)__hip_atomic_fetch_add(&accL[local], u, __ATOMIC_RELAXED, __HIP_MEMORY_SCOPE_WORKGROUP);
}

__global__ __launch_bounds__(BLOCK) void accum_kernel(const uint2* __restrict__ records,
                             const int* __restrict__ cnt, int N, int cap,
                             float* __restrict__ partials, int store_mode) {
    __shared__ unsigned long long accL[TILE];
    int b = blockIdx.x >> 2;          // KSLICE == 4
    int k = blockIdx.x & 3;
    int tid = threadIdx.x;
    int lo = (int)(((long long)b * N + NB - 1) / NB);
    int hi = (int)(((long long)(b + 1) * N + NB - 1) / NB);
    if (hi > N) hi = N;
    int span = hi - lo;
    for (int i = tid; i < span; i += BLOCK) accL[i] = 0ULL;
    __syncthreads();
    int c = cnt[b];
    int per = (((c + KSLICE - 1) / KSLICE) + 1) & ~1;  // even -> slice start 16B-aligned
    int s0i = k * per; if (s0i > c) s0i = c;
    int s1i = s0i + per; if (s1i > c) s1i = c;
    int myc = s1i - s0i;
    const uint2* r = records + (size_t)b * cap + s0i;
    int lo16 = lo & 0xFFFF;
    const uint4* r4 = (const uint4*)r;
    int pairs = myc >> 1;
    int i = tid;
    for (; i + 3 * BLOCK < pairs; i += 4 * BLOCK) {
        uint4 f0 = r4[i];
        uint4 f1 = r4[i + BLOCK];
        uint4 f2 = r4[i + 2 * BLOCK];
        uint4 f3 = r4[i + 3 * BLOCK];
        accum_rec(accL, f0.x, f0.y, lo16); accum_rec(accL, f0.z, f0.w, lo16);
        accum_rec(accL, f1.x, f1.y, lo16); accum_rec(accL, f1.z, f1.w, lo16);
        accum_rec(accL, f2.x, f2.y, lo16); accum_rec(accL, f2.z, f2.w, lo16);
        accum_rec(accL, f3.x, f3.y, lo16); accum_rec(accL, f3.z, f3.w, lo16);
    }
    for (; i < pairs; i += BLOCK) {
        uint4 f = r4[i];
        accum_rec(accL, f.x, f.y, lo16); accum_rec(accL, f.z, f.w, lo16);
    }
    if (tid == 0 && (myc & 1)) {
        uint2 f = r[myc - 1];
        accum_rec(accL, f.x, f.y, lo16);
    }
    __syncthreads();
    float* g = partials + (size_t)k * N * 3 + (size_t)lo * 3;
    for (int t = tid; t < span; t += BLOCK) {
        unsigned long long u = accL[t];
        int cc = (int)(unsigned)(u >> 54);
        int q0 = (int)((u >> 36) & 0x3FFFF);
        int q1 = (int)((u >> 18) & 0x3FFFF);
        int q2 = (int)(u & 0x3FFFF);
        float f0 = (float)(q0 - 512 * cc) * 0.03125f;
        float f1 = (float)(q1 - 512 * cc) * 0.03125f;
        float f2 = (float)(q2 - 512 * cc) * 0.03125f;
        if (store_mode) {
            g[t * 3 + 0] = f0; g[t * 3 + 1] = f1; g[t * 3 + 2] = f2;
        } else {
            g[t * 3 + 0] += f0; g[t * 3 + 1] += f1; g[t * 3 + 2] += f2;
        }
    }
}

// ---------------- fallback scatter (device atomics) ----------------
__global__ void scatter_kernel(const float* __restrict__ scaled,
                               const float* __restrict__ general_ops,
                               const int* __restrict__ symm_map,
                               float* __restrict__ acc,
                               long long total, int O) {
    __shared__ float rot_s[64 * 9];
    for (int i = threadIdx.x; i < O * 9; i += blockDim.x) {
        int o = i / 9, r = i - o * 9;
        rot_s[i] = general_ops[o * 16 + (r / 3) * 4 + (r % 3)];
    }
    __syncthreads();
    long long t = (long long)blockIdx.x * blockDim.x + threadIdx.x;
    if (t >= total) return;
    long long n = t / O;
    int o = (int)(t - n * O);
    float s0 = scaled[n * 3 + 0], s1 = scaled[n * 3 + 1], s2 = scaled[n * 3 + 2];
    const float* R = rot_s + o * 9;
    float v0 = R[0] * s0 + R[1] * s1 + R[2] * s2;
    float v1 = R[3] * s0 + R[4] * s1 + R[5] * s2;
    float v2 = R[6] * s0 + R[7] * s1 + R[8] * s2;
    int tgt = symm_map[t];
    atomicAdd(&acc[(size_t)tgt * 3 + 0], v0);
    atomicAdd(&acc[(size_t)tgt * 3 + 1], v1);
    atomicAdd(&acc[(size_t)tgt * 3 + 2], v2);
}

// ---------------- out = lat^T (sum_k partial_k / count) ----------------
__global__ void output_kernel(const float* __restrict__ lat,
                              const int* __restrict__ num_general_ops,
                              const int* __restrict__ offsets, int B, int N,
                              const float* __restrict__ partials, int K,
                              float* __restrict__ out) {
    int n = blockIdx.x * blockDim.x + threadIdx.x;
    if (n >= N) return;
    int b = find_batch(offsets, B, n);
    float inv_cnt = 1.0f / (float)num_general_ops[b];
    float a0 = 0.f, a1 = 0.f, a2 = 0.f;
    for (int k = 0; k < K; ++k) {
        const float* a = partials + (size_t)k * N * 3;
        a0 += a[n * 3 + 0]; a1 += a[n * 3 + 1]; a2 += a[n * 3 + 2];
    }
    a0 *= inv_cnt; a1 *= inv_cnt; a2 *= inv_cnt;
    const float* M = lat + (size_t)b * 9;
    out[n * 3 + 0] = M[0] * a0 + M[3] * a1 + M[6] * a2;
    out[n * 3 + 1] = M[1] * a0 + M[4] * a1 + M[7] * a2;
    out[n * 3 + 2] = M[2] * a0 + M[5] * a1 + M[8] * a2;
}

static inline size_t align16(size_t x) { return (x + 15) & ~(size_t)15; }

extern "C" void kernel_launch(void* const* d_in, const int* in_sizes, int n_in,
                              void* d_out, int out_size, void* d_ws, size_t ws_size,
                              hipStream_t stream) {
    const float* lattices        = (const float*)d_in[0];
    const float* inv_lattices    = (const float*)d_in[1];
    const float* forces          = (const float*)d_in[2];
    const int*   num_atoms       = (const int*)d_in[3];
    const float* general_ops     = (const float*)d_in[4];
    const int*   symm_map        = (const int*)d_in[5];
    const int*   num_general_ops = (const int*)d_in[6];

    int B = in_sizes[0] / 9;
    int N = in_sizes[2] / 3;
    int O = in_sizes[4] / 16;
    long long total = (long long)N * O;

    // ---- workspace layout ----
    char* p = (char*)d_ws;
    size_t used = 0;
    float* scaled   = (float*)(p + used); used = align16(used + (size_t)N * 3 * sizeof(float));
    float* partials = (float*)(p + used); used = align16(used + (size_t)KS_TOT * N * 3 * sizeof(float));
    int* offsets    = (int*)(p + used);   used = align16(used + (size_t)(B + 1) * sizeof(int));
    int* hist       = (int*)(p + used);   used = align16(used + (size_t)GP * NB * sizeof(int));
    int* offs       = (int*)(p + used);   used = align16(used + (size_t)GP * NB * sizeof(int));
    int* cnt        = (int*)(p + used);   used = align16(used + (size_t)NB * sizeof(int));
    size_t remaining = (ws_size > used) ? ws_size - used : 0;

    // choose chunk count C so 8B records fit; cap = mean + 25% + 512 slack, even
    const long long quantum = 4 * BLOCK;
    int C = -1, cap = 0;
    long long chunk_nom = 0;
    for (int c = 1; c <= 64; ++c) {
        long long cp = (total + c - 1) / c;
        cp = (cp + quantum - 1) / quantum * quantum;
        long long mean = (cp + NB - 1) / NB;
        long long capc = mean + mean / 4 + 512;
        capc = (capc + 1) & ~1LL;  // even, for uint4 alignment
        if ((size_t)NB * capc * sizeof(uint2) <= remaining) { C = c; cap = (int)capc; chunk_nom = cp; break; }
    }
    bool fast = (C > 0) && ((long long)N <= (long long)NB * TILE) && (O <= 64) && (total < (1LL << 31));

    int gridN = (N + BLOCK - 1) / BLOCK;
    scan_offsets_kernel<<<1, 1024, 0, stream>>>(num_atoms, B, offsets);

    if (fast) {
        uint2* records = (uint2*)(p + used);
        float* ovf = partials + (size_t)KSLICE * N * 3;
        int store_mode = (C == 1) ? 1 : 0;
        int zf = store_mode ? KSLICE : 0;    // store-mode: only zero overflow slice
        scale_kernel<<<gridN, BLOCK, 0, stream>>>(inv_lattices, forces, offsets, B, N,
                                                  scaled, partials, zf, KS_TOT);
        for (int c = 0; c < C; ++c) {
            long long base = (long long)c * chunk_nom;
            if (base >= total) break;
            long long rem = total - base;
            int cp = (int)((rem < chunk_nom) ? rem : chunk_nom);
            hist_kernel<<<GP, BLOCK, 0, stream>>>(symm_map, base, cp, N, hist);
            scan_cols_kernel<<<NB, BLOCK, 0, stream>>>(hist, cap, offs, cnt);
            place_kernel<<<GP, BLOCK, 0, stream>>>(symm_map, scaled, general_ops, offs,
                                                   base, cp, N, O, cap, records, ovf);
            accum_kernel<<<NB * KSLICE, BLOCK, 0, stream>>>(records, cnt, N, cap, partials, store_mode);
        }
        output_kernel<<<gridN, BLOCK, 0, stream>>>(lattices, num_general_ops, offsets, B, N,
                                                   partials, KS_TOT, (float*)d_out);
    } else {
        // fallback: device-atomic scatter into partials[0]
        scale_kernel<<<gridN, BLOCK, 0, stream>>>(inv_lattices, forces, offsets, B, N,
                                                  scaled, partials, 0, 1);
        long long gridS = (total + BLOCK - 1) / BLOCK;
        scatter_kernel<<<(int)gridS, BLOCK, 0, stream>>>(scaled, general_ops, symm_map, partials, total, O);
        output_kernel<<<gridN, BLOCK, 0, stream>>>(lattices, num_general_ops, offsets, B, N,
                                                   partials, 1, (float*)d_out);
    }
}

// Round 7
// 986.141 us; speedup vs baseline: 1.7767x; 1.2431x over previous
//
#include <hip/hip_runtime.h>
#include <hip/hip_fp16.h>
#include <math.h>

#define BLOCK 256
#define NB 256         // target buckets; open runs = GP*NB = 131K < 262K L2 lines
#define TILE 4096      // atoms per bucket tile (ceil(N/NB) must fit)
#define GP 512         // producer blocks for place
#define KSLICE 8       // accum slices per bucket
#define KS_TOT (KSLICE + 1)   // + overflow partial
#define GPK (GP / KSLICE)     // producer blocks per accum slice

// ---------------- offsets scan (tiny) ----------------
__global__ void scan_offsets_kernel(const int* __restrict__ num_atoms, int B,
                                    int* __restrict__ offsets) {
    __shared__ long long partial[1024];
    int t = threadIdx.x;
    int per = (B + 1023) / 1024;
    int base_idx = t * per;
    long long local = 0;
    for (int i = 0; i < per; ++i) {
        int idx = base_idx + i;
        if (idx < B) local += num_atoms[idx];
    }
    partial[t] = local;
    __syncthreads();
    for (int d = 1; d < 1024; d <<= 1) {
        long long v = (t >= d) ? partial[t - d] : 0;
        __syncthreads();
        partial[t] += v;
        __syncthreads();
    }
    long long run = (t == 0) ? 0 : partial[t - 1];
    for (int i = 0; i < per; ++i) {
        int idx = base_idx + i;
        if (idx < B) {
            offsets[idx] = (int)run;
            run += num_atoms[idx];
        }
    }
    if (t == 1023) offsets[B] = (int)partial[1023];
}

__device__ __forceinline__ int find_batch(const int* __restrict__ offsets, int B, int n) {
    int lo = 0, hi = B;
    while (hi - lo > 1) {
        int mid = (lo + hi) >> 1;
        if (offsets[mid] <= n) lo = mid; else hi = mid;
    }
    return lo;
}

// ---------------- scaled = inv_lat^T f ; zero partial slices [zf,zt) ----------------
__global__ void scale_kernel(const float* __restrict__ inv_lat,
                             const float* __restrict__ forces,
                             const int* __restrict__ offsets, int B, int N,
                             float* __restrict__ scaled, float* __restrict__ partials,
                             int zf, int zt) {
    int n = blockIdx.x * blockDim.x + threadIdx.x;
    if (n >= N) return;
    int b = find_batch(offsets, B, n);
    const float* M = inv_lat + (size_t)b * 9;
    float f0 = forces[n * 3 + 0], f1 = forces[n * 3 + 1], f2 = forces[n * 3 + 2];
    float s0 = M[0] * f0 + M[3] * f1 + M[6] * f2;
    float s1 = M[1] * f0 + M[4] * f1 + M[7] * f2;
    float s2 = M[2] * f0 + M[5] * f1 + M[8] * f2;
    scaled[n * 3 + 0] = s0; scaled[n * 3 + 1] = s1; scaled[n * 3 + 2] = s2;
    for (int k = zf; k < zt; ++k) {
        float* a = partials + (size_t)k * N * 3;
        a[n * 3 + 0] = 0.f; a[n * 3 + 1] = 0.f; a[n * 3 + 2] = 0.f;
    }
}

__device__ __forceinline__ int bucket_of(int tgt, int N) {
    return (int)(((unsigned long long)(unsigned)tgt * (unsigned)NB) / (unsigned)N);
}

// ---------------- record emit (value-check BEFORE slot claim; regions stay dense) ----------------
__device__ __forceinline__ void emit_record(uint2* __restrict__ records,
                                            float* __restrict__ ovf,
                                            int* cur, const int* lim,
                                            int tgt, int bb,
                                            float v0, float v1, float v2) {
    float m = fmaxf(fmaxf(fabsf(v0), fabsf(v1)), fabsf(v2));
    if (m < 15.0f) {
        int pos = atomicAdd(&cur[bb], 1);
        if (pos < lim[bb]) {
            unsigned x = (unsigned)__half_as_ushort(__float2half_rn(v0)) |
                         ((unsigned)__half_as_ushort(__float2half_rn(v1)) << 16);
            unsigned y = (unsigned)__half_as_ushort(__float2half_rn(v2)) |
                         (((unsigned)tgt & 0xFFFFu) << 16);
            records[pos] = make_uint2(x, y);
            return;
        }
    }
    atomicAdd(&ovf[(size_t)tgt * 3 + 0], v0);
    atomicAdd(&ovf[(size_t)tgt * 3 + 1], v1);
    atomicAdd(&ovf[(size_t)tgt * 3 + 2], v2);
}

// ---------------- place: single pass, per-(block,bucket) record regions, no hist ----------------
__global__ __launch_bounds__(BLOCK) void place_kernel(const int* __restrict__ symm_map,
                             const float* __restrict__ scaled,
                             const float* __restrict__ general_ops,
                             long long chunk_base, int chunk_pairs, int N, int O, int cap,
                             uint2* __restrict__ records, int* __restrict__ cnts,
                             float* __restrict__ ovf) {
    __shared__ int cur[NB];
    __shared__ int lim[NB];
    __shared__ float R[64 * 9];
    int tid = threadIdx.x, g = blockIdx.x;
    for (int i = tid; i < O * 9; i += BLOCK) {
        int o = i / 9, r = i - o * 9;
        R[i] = general_ops[o * 16 + (r / 3) * 4 + (r % 3)];
    }
    for (int i = tid; i < NB; i += BLOCK) {
        int base = (i * GP + g) * cap;
        cur[i] = base;
        lim[i] = base + cap;
    }
    __syncthreads();
    int nblk = gridDim.x;
    const int quantum = 4 * BLOCK;
    int span = (int)(((long long)chunk_pairs + (long long)nblk * quantum - 1) / ((long long)nblk * quantum)) * quantum;
    long long bs = (long long)g * span;
    int cnt = (int)((chunk_pairs - bs) < (long long)span ? (chunk_pairs - bs) : (long long)span);
    if (cnt > 0) {
        const int* p = symm_map + chunk_base + bs;
        unsigned tbase = (unsigned)(chunk_base + bs);
        unsigned uO = (unsigned)O;
        int i0 = tid * 4;
        unsigned t0 = tbase + (unsigned)i0;
        unsigned n = t0 / uO;
        unsigned o = t0 - n * uO;
        unsigned dq = (unsigned)quantum / uO;
        unsigned rq = (unsigned)quantum - dq * uO;
        for (; i0 + 4 <= cnt; i0 += quantum) {
            int4 tg = *(const int4*)(p + i0);
            unsigned nn = n, oo = o;
            #pragma unroll
            for (int j = 0; j < 4; ++j) {
                int tgt = (j == 0) ? tg.x : (j == 1) ? tg.y : (j == 2) ? tg.z : tg.w;
                const float* Ro = R + oo * 9;
                float s0 = scaled[nn * 3 + 0], s1 = scaled[nn * 3 + 1], s2 = scaled[nn * 3 + 2];
                float v0 = Ro[0] * s0 + Ro[1] * s1 + Ro[2] * s2;
                float v1 = Ro[3] * s0 + Ro[4] * s1 + Ro[5] * s2;
                float v2 = Ro[6] * s0 + Ro[7] * s1 + Ro[8] * s2;
                emit_record(records, ovf, cur, lim, tgt, bucket_of(tgt, N), v0, v1, v2);
                if (++oo == uO) { oo = 0; ++nn; }
            }
            o += rq;
            if (o >= uO) { o -= uO; n += dq + 1; } else n += dq;
        }
        if (i0 < cnt) {
            unsigned nn = n, oo = o;
            for (int j = i0; j < cnt; ++j) {
                int tgt = p[j];
                const float* Ro = R + oo * 9;
                float s0 = scaled[nn * 3 + 0], s1 = scaled[nn * 3 + 1], s2 = scaled[nn * 3 + 2];
                float v0 = Ro[0] * s0 + Ro[1] * s1 + Ro[2] * s2;
                float v1 = Ro[3] * s0 + Ro[4] * s1 + Ro[5] * s2;
                float v2 = Ro[6] * s0 + Ro[7] * s1 + Ro[8] * s2;
                emit_record(records, ovf, cur, lim, tgt, bucket_of(tgt, N), v0, v1, v2);
                if (++oo == uO) { oo = 0; ++nn; }
            }
        }
    }
    __syncthreads();
    // ALWAYS write counts (poisoned ws must not leak into accum)
    for (int i = tid; i < NB; i += BLOCK) {
        int base = lim[i] - cap;
        int c = cur[i] - base;
        if (c > cap) c = cap;
        if (c < 0) c = 0;
        cnts[(size_t)i * GP + g] = c;
    }
}

// ---------------- accum: (bucket, slice) -> packed-u64 LDS tile over 64 fragments ----------------
// accL word: [count:10 | q0:18 | q1:18 | q2:18], q = round((v+16)*32) in [0,1024)
__device__ __forceinline__ void accum_rec(unsigned long long* accL,
                                          unsigned x, unsigned y, int lo16) {
    float v0 = __half2float(__ushort_as_half((unsigned short)(x & 0xFFFF)));
    float v1 = __half2float(__ushort_as_half((unsigned short)(x >> 16)));
    float v2 = __half2float(__ushort_as_half((unsigned short)(y & 0xFFFF)));
    int local = ((int)(y >> 16) - lo16) & 0xFFFF;
    unsigned q0 = (unsigned)(int)rintf(fminf(fmaxf(v0, -15.97f), 15.96f) * 32.f + 512.f);
    unsigned q1 = (unsigned)(int)rintf(fminf(fmaxf(v1, -15.97f), 15.96f) * 32.f + 512.f);
    unsigned q2 = (unsigned)(int)rintf(fminf(fmaxf(v2, -15.97f), 15.96f) * 32.f + 512.f);
    unsigned long long u = (1ULL << 54) | ((unsigned long long)q0 << 36)
                         | ((unsigned long long)q1 << 18) | (unsigned long long)q2;
    (void)__hip_atomic_fetch_add(&accL[local], u, __ATOMIC_RELAXED, __HIP_MEMORY_SCOPE_WORKGROUP);
}

__global__ __launch_bounds__(BLOCK) void accum_kernel(const uint2* __restrict__ records,
                             const int* __restrict__ cnts, int N, int cap,
                             float* __restrict__ partials, int store_mode) {
    __shared__ unsigned long long accL[TILE];
    int b = blockIdx.x / KSLICE;
    int k = blockIdx.x - b * KSLICE;
    int tid = threadIdx.x;
    int lo = (int)(((long long)b * N + NB - 1) / NB);
    int hi = (int)(((long long)(b + 1) * N + NB - 1) / NB);
    if (hi > N) hi = N;
    int span = hi - lo;
    for (int i = tid; i < span; i += BLOCK) accL[i] = 0ULL;
    __syncthreads();
    int lo16 = lo & 0xFFFF;
    int g0 = k * GPK;
    for (int g = g0; g < g0 + GPK; ++g) {
        int c = cnts[(size_t)b * GP + g];
        const uint2* r = records + ((size_t)b * GP + g) * (size_t)cap;
        const uint4* r4 = (const uint4*)r;
        int pairs = c >> 1;
        for (int i = tid; i < pairs; i += BLOCK) {
            uint4 f = r4[i];
            accum_rec(accL, f.x, f.y, lo16);
            accum_rec(accL, f.z, f.w, lo16);
        }
        if (tid == 0 && (c & 1)) {
            uint2 f = r[c - 1];
            accum_rec(accL, f.x, f.y, lo16);
        }
    }
    __syncthreads();
    float* gp = partials + (size_t)k * N * 3 + (size_t)lo * 3;
    for (int t = tid; t < span; t += BLOCK) {
        unsigned long long u = accL[t];
        int cc = (int)(unsigned)(u >> 54);
        int q0 = (int)((u >> 36) & 0x3FFFF);
        int q1 = (int)((u >> 18) & 0x3FFFF);
        int q2 = (int)(u & 0x3FFFF);
        float f0 = (float)(q0 - 512 * cc) * 0.03125f;
        float f1 = (float)(q1 - 512 * cc) * 0.03125f;
        float f2 = (float)(q2 - 512 * cc) * 0.03125f;
        if (store_mode) {
            gp[t * 3 + 0] = f0; gp[t * 3 + 1] = f1; gp[t * 3 + 2] = f2;
        } else {
            gp[t * 3 + 0] += f0; gp[t * 3 + 1] += f1; gp[t * 3 + 2] += f2;
        }
    }
}

// ---------------- fallback scatter (device atomics) ----------------
__global__ void scatter_kernel(const float* __restrict__ scaled,
                               const float* __restrict__ general_ops,
                               const int* __restrict__ symm_map,
                               float* __restrict__ acc,
                               long long total, int O) {
    __shared__ float rot_s[64 * 9];
    for (int i = threadIdx.x; i < O * 9; i += blockDim.x) {
        int o = i / 9, r = i - o * 9;
        rot_s[i] = general_ops[o * 16 + (r / 3) * 4 + (r % 3)];
    }
    __syncthreads();
    long long t = (long long)blockIdx.x * blockDim.x + threadIdx.x;
    if (t >= total) return;
    long long n = t / O;
    int o = (int)(t - n * O);
    float s0 = scaled[n * 3 + 0], s1 = scaled[n * 3 + 1], s2 = scaled[n * 3 + 2];
    const float* R = rot_s + o * 9;
    float v0 = R[0] * s0 + R[1] * s1 + R[2] * s2;
    float v1 = R[3] * s0 + R[4] * s1 + R[5] * s2;
    float v2 = R[6] * s0 + R[7] * s1 + R[8] * s2;
    int tgt = symm_map[t];
    atomicAdd(&acc[(size_t)tgt * 3 + 0], v0);
    atomicAdd(&acc[(size_t)tgt * 3 + 1], v1);
    atomicAdd(&acc[(size_t)tgt * 3 + 2], v2);
}

// ---------------- out = lat^T (sum_k partial_k / count) ----------------
__global__ void output_kernel(const float* __restrict__ lat,
                              const int* __restrict__ num_general_ops,
                              const int* __restrict__ offsets, int B, int N,
                              const float* __restrict__ partials, int K,
                              float* __restrict__ out) {
    int n = blockIdx.x * blockDim.x + threadIdx.x;
    if (n >= N) return;
    int b = find_batch(offsets, B, n);
    float inv_cnt = 1.0f / (float)num_general_ops[b];
    float a0 = 0.f, a1 = 0.f, a2 = 0.f;
    for (int k = 0; k < K; ++k) {
        const float* a = partials + (size_t)k * N * 3;
        a0 += a[n * 3 + 0]; a1 += a[n * 3 + 1]; a2 += a[n * 3 + 2];
    }
    a0 *= inv_cnt; a1 *= inv_cnt; a2 *= inv_cnt;
    const float* M = lat + (size_t)b * 9;
    out[n * 3 + 0] = M[0] * a0 + M[3] * a1 + M[6] * a2;
    out[n * 3 + 1] = M[1] * a0 + M[4] * a1 + M[7] * a2;
    out[n * 3 + 2] = M[2] * a0 + M[5] * a1 + M[8] * a2;
}

static inline size_t align16(size_t x) { return (x + 15) & ~(size_t)15; }

extern "C" void kernel_launch(void* const* d_in, const int* in_sizes, int n_in,
                              void* d_out, int out_size, void* d_ws, size_t ws_size,
                              hipStream_t stream) {
    const float* lattices        = (const float*)d_in[0];
    const float* inv_lattices    = (const float*)d_in[1];
    const float* forces          = (const float*)d_in[2];
    const int*   num_atoms       = (const int*)d_in[3];
    const float* general_ops     = (const float*)d_in[4];
    const int*   symm_map        = (const int*)d_in[5];
    const int*   num_general_ops = (const int*)d_in[6];

    int B = in_sizes[0] / 9;
    int N = in_sizes[2] / 3;
    int O = in_sizes[4] / 16;
    long long total = (long long)N * O;

    // ---- workspace layout ----
    char* p = (char*)d_ws;
    size_t used = 0;
    float* scaled   = (float*)(p + used); used = align16(used + (size_t)N * 3 * sizeof(float));
    float* partials = (float*)(p + used); used = align16(used + (size_t)KS_TOT * N * 3 * sizeof(float));
    int* offsets    = (int*)(p + used);   used = align16(used + (size_t)(B + 1) * sizeof(int));
    int* cnts       = (int*)(p + used);   used = align16(used + (size_t)NB * GP * sizeof(int));
    size_t remaining = (ws_size > used) ? ws_size - used : 0;

    // chunk count C so per-(block,bucket) regions fit: cap = mean + 5*sqrt(mean) + 16, even
    const long long quantum = 4 * BLOCK;
    int C = -1, cap = 0;
    long long chunk_nom = 0;
    for (int c = 1; c <= 64; ++c) {
        long long cp = (total + c - 1) / c;
        cp = (cp + quantum - 1) / quantum * quantum;           // quantum-aligned chunk
        long long pb = ((cp + (long long)GP * quantum - 1) / ((long long)GP * quantum)) * quantum;  // per-block span
        double m = (double)pb / (double)NB;
        long long capc = (long long)(m + 5.0 * sqrt(m > 1.0 ? m : 1.0) + 16.0);
        capc = (capc + 1) & ~1LL;                              // even -> 16B-aligned fragments
        if ((size_t)NB * (size_t)GP * (size_t)capc * sizeof(uint2) <= remaining) {
            C = c; cap = (int)capc; chunk_nom = cp; break;
        }
    }
    bool fast = (C > 0) && (((long long)N + NB - 1) / NB <= TILE) && (O <= 64)
                && (total < (1LL << 31))
                && ((long long)NB * GP * cap < (1LL << 31));

    int gridN = (N + BLOCK - 1) / BLOCK;
    scan_offsets_kernel<<<1, 1024, 0, stream>>>(num_atoms, B, offsets);

    if (fast) {
        uint2* records = (uint2*)(p + used);
        float* ovf = partials + (size_t)KSLICE * N * 3;
        int store_mode = (C == 1) ? 1 : 0;
        int zf = store_mode ? KSLICE : 0;    // store-mode: only zero overflow slice
        scale_kernel<<<gridN, BLOCK, 0, stream>>>(inv_lattices, forces, offsets, B, N,
                                                  scaled, partials, zf, KS_TOT);
        for (int c = 0; c < C; ++c) {
            long long base = (long long)c * chunk_nom;
            if (base >= total) break;
            long long rem = total - base;
            int cp = (int)((rem < chunk_nom) ? rem : chunk_nom);
            place_kernel<<<GP, BLOCK, 0, stream>>>(symm_map, scaled, general_ops,
                                                   base, cp, N, O, cap, records, cnts, ovf);
            accum_kernel<<<NB * KSLICE, BLOCK, 0, stream>>>(records, cnts, N, cap,
                                                            partials, store_mode);
        }
        output_kernel<<<gridN, BLOCK, 0, stream>>>(lattices, num_general_ops, offsets, B, N,
                                                   partials, KS_TOT, (float*)d_out);
    } else {
        // fallback: device-atomic scatter into partials[0]
        scale_kernel<<<gridN, BLOCK, 0, stream>>>(inv_lattices, forces, offsets, B, N,
                                                  scaled, partials, 0, 1);
        long long gridS = (total + BLOCK - 1) / BLOCK;
        scatter_kernel<<<(int)gridS, BLOCK, 0, stream>>>(scaled, general_ops, symm_map, partials, total, O);
        output_kernel<<<gridN, BLOCK, 0, stream>>>(lattices, num_general_ops, offsets, B, N,
                                                   partials, 1, (float*)d_out);
    }
}